// Round 3
// baseline (4317.163 us; speedup 1.0000x reference)
//
#include <hip/hip_runtime.h>
#include <math.h>

#define LR_C 0.1f
#define WINDOW_C 10
#define NH 512
#define NBLK 8   // 512 units / 64 lanes
#define WAVE 64
#define ALPHA (-1.44269504088896340736f)  // -log2(e)

typedef _Float16 half_t;

// Scaled space: W = ALPHA*w, y_t = W[t]·x_t, h_t = 1/(1+2^{y_t}),
// W[t+1] = W[t] + h_t*cx_t  with cx_t = ALPHA*LR*r_t*x_t.
// Lookahead: y_{t+1} = W[t]·x_{t+1} + h_t*d_t,  d_t = cx_t·x_{t+1} (uniform).
//
// prep: pk[t] = {x0[t+1], x1[t+1], cx0[t], cx1[t]},  dv[t] = cx0*x0[t+1]+cx1*x1[t+1]
__global__ void prep_kernel(const float* __restrict__ X,
                            const float* __restrict__ rewards,
                            float4* __restrict__ pk, float* __restrict__ dv, int T) {
    int t = blockIdx.x * blockDim.x + threadIdx.x;
    if (t >= T) return;
    int lo = t - (WINDOW_C - 1); if (lo < 0) lo = 0;
    float s = 0.0f;
    for (int k = lo; k <= t; ++k) s += rewards[k];
    float r = rewards[t] - s / (float)(t - lo + 1);
    float c = ALPHA * LR_C * r;
    float cx0 = c * X[2 * t];
    float cx1 = c * X[2 * t + 1];
    float xn0 = 0.0f, xn1 = 0.0f;
    if (t + 1 < T) { xn0 = X[2 * t + 2]; xn1 = X[2 * t + 3]; }
    pk[t] = make_float4(xn0, xn1, cx0, cx1);
    dv[t] = fmaf(cx1, xn1, cx0 * xn0);
}

// MODE 0: store h as fp16, transposed hall[unit][t]; one 16B store / 8 iters.
// MODE 1 (fallback): in-wave shuffle reduction, lane0 stores partial[b*T+t].
template <int MODE>
__global__ __launch_bounds__(WAVE) void scan_kernel(const float* __restrict__ Winit,
                                                    const float* __restrict__ X,
                                                    const float4* __restrict__ pk,
                                                    const float* __restrict__ dv,
                                                    void* __restrict__ sinkp, int T) {
    const int lane = threadIdx.x;
    const int b = blockIdx.x;
    const int i = b * WAVE + lane;
    float W0 = ALPHA * Winit[2 * i];
    float W1 = ALPHA * Winit[2 * i + 1];
    float u = fmaf(W1, X[1], W0 * X[0]);   // y_0 = W[0]·x_0
    float h = 0.0f, dpv = 0.0f, cxp0 = 0.0f, cxp1 = 0.0f;

    half_t* __restrict__ hrow = (half_t*)sinkp + (size_t)i * T;  // MODE 0
    float*  __restrict__ prow = (float*)sinkp + (size_t)b * T;   // MODE 1

    float4 pA[8], pB[8];
    float4 dA[2], dB[2];
    float hh[8];
    const int T16 = T & ~15;

#define BODY(P, D, TT)                                                        \
    {                                                                         \
        _Pragma("unroll")                                                     \
        for (int j = 0; j < 8; ++j) {                                         \
            float y = fmaf(h, dpv, u);          /* chain op 1 */              \
            W0 = fmaf(h, cxp0, W0);             /* off-chain: W[t] */         \
            W1 = fmaf(h, cxp1, W1);                                           \
            u = fmaf(W1, P[j].y, W0 * P[j].x);  /* off-chain: W[t]·x[t+1] */  \
            float e = __builtin_amdgcn_exp2f(y);/* chain op 2 */              \
            h = __builtin_amdgcn_rcpf(1.0f + e);/* chain ops 3,4 */           \
            hh[j] = h;                                                        \
            cxp0 = P[j].z; cxp1 = P[j].w; dpv = D[j >> 2][j & 3];             \
        }                                                                     \
        if (MODE == 0) {                                                      \
            union { half_t hx[8]; float4 v; } cv;                             \
            _Pragma("unroll")                                                 \
            for (int j = 0; j < 8; ++j) cv.hx[j] = (half_t)hh[j];             \
            *(float4*)(hrow + (TT)) = cv.v;                                   \
        } else {                                                              \
            _Pragma("unroll")                                                 \
            for (int j = 0; j < 8; ++j) {                                     \
                float s = hh[j];                                              \
                _Pragma("unroll")                                             \
                for (int m = 1; m < WAVE; m <<= 1) s += __shfl_xor(s, m, WAVE); \
                hh[j] = s;                                                    \
            }                                                                 \
            if (lane == 0) {                                                  \
                _Pragma("unroll")                                             \
                for (int j = 0; j < 8; ++j) prow[(TT) + j] = hh[j];           \
            }                                                                 \
        }                                                                     \
    }

    if (T16 >= 16) {
        #pragma unroll
        for (int j = 0; j < 8; ++j) pA[j] = pk[j];
        dA[0] = *(const float4*)(dv + 0);
        dA[1] = *(const float4*)(dv + 4);
    }
    for (int t0 = 0; t0 < T16; t0 += 16) {
        #pragma unroll
        for (int j = 0; j < 8; ++j) pB[j] = pk[t0 + 8 + j];
        dB[0] = *(const float4*)(dv + t0 + 8);
        dB[1] = *(const float4*)(dv + t0 + 12);
        BODY(pA, dA, t0)
        if (t0 + 16 < T16) {
            #pragma unroll
            for (int j = 0; j < 8; ++j) pA[j] = pk[t0 + 16 + j];
            dA[0] = *(const float4*)(dv + t0 + 16);
            dA[1] = *(const float4*)(dv + t0 + 20);
        }
        BODY(pB, dB, t0 + 8)
    }
#undef BODY
    // tail
    for (int t = T16; t < T; ++t) {
        float4 p = pk[t];
        float d = dv[t];
        float y = fmaf(h, dpv, u);
        W0 = fmaf(h, cxp0, W0);
        W1 = fmaf(h, cxp1, W1);
        u = fmaf(W1, p.y, W0 * p.x);
        float e = __builtin_amdgcn_exp2f(y);
        h = __builtin_amdgcn_rcpf(1.0f + e);
        if (MODE == 0) {
            hrow[t] = (half_t)h;
        } else {
            float s = h;
            #pragma unroll
            for (int m = 1; m < WAVE; m <<= 1) s += __shfl_xor(s, m, WAVE);
            if (lane == 0) prow[t] = s;
        }
        cxp0 = p.z; cxp1 = p.w; dpv = d;
    }
}

// MODE 0 finisher: each thread sums 8 consecutive t over all 512 unit-rows.
__global__ __launch_bounds__(256) void final_vec(const half_t* __restrict__ hall,
                                                 float* __restrict__ out, int T, int Tv) {
    int g = blockIdx.x * blockDim.x + threadIdx.x;
    int t0 = g * 8;
    if (t0 >= Tv) return;
    float s[8] = {0, 0, 0, 0, 0, 0, 0, 0};
    for (int u = 0; u < NH; ++u) {
        union { float4 v; half_t hx[8]; } cv;
        cv.v = *(const float4*)(hall + (size_t)u * T + t0);
        #pragma unroll
        for (int j = 0; j < 8; ++j) s[j] += (float)cv.hx[j];
    }
    float4 o0 = make_float4(s[0], s[1], s[2], s[3]);
    float4 o1 = make_float4(s[4], s[5], s[6], s[7]);
    const float inv = 1.0f / (float)NH;
    o0.x *= inv; o0.y *= inv; o0.z *= inv; o0.w *= inv;
    o1.x *= inv; o1.y *= inv; o1.z *= inv; o1.w *= inv;
    *(float4*)(out + t0) = o0;
    *(float4*)(out + t0 + 4) = o1;
}

__global__ void final_sca(const half_t* __restrict__ hall,
                          float* __restrict__ out, int T, int tstart) {
    int t = tstart + blockIdx.x * blockDim.x + threadIdx.x;
    if (t >= T) return;
    float s = 0.0f;
    for (int u = 0; u < NH; ++u) s += (float)hall[(size_t)u * T + t];
    out[t] = s * (1.0f / (float)NH);
}

// MODE 1 finisher: sum the 8 per-block rows.
__global__ void final_part(const float* __restrict__ partial,
                           float* __restrict__ out, int T) {
    int t = blockIdx.x * blockDim.x + threadIdx.x;
    if (t >= T) return;
    float s = 0.0f;
    #pragma unroll
    for (int b = 0; b < NBLK; ++b) s += partial[(size_t)b * T + t];
    out[t] = s * (1.0f / (float)NH);
}

extern "C" void kernel_launch(void* const* d_in, const int* in_sizes, int n_in,
                              void* d_out, int out_size, void* d_ws, size_t ws_size,
                              hipStream_t stream) {
    const float* X       = (const float*)d_in[0];
    const float* rewards = (const float*)d_in[1];
    const float* Winit   = (const float*)d_in[2];
    float* out = (float*)d_out;
    const int T = in_sizes[1];

    float4* pk = (float4*)d_ws;
    float* dvp = (float*)((char*)d_ws + 16ull * (size_t)T);
    void* sink = (void*)((char*)d_ws + 20ull * (size_t)T);

    const size_t need0 = 20ull * T + 2ull * NH * T;   // pk + dv + fp16 hall (~104 MB @ T=1e5)
    const bool mode0 = (ws_size >= need0) && (T % 8 == 0);

    int threads = 256;
    int blocks = (T + threads - 1) / threads;
    prep_kernel<<<blocks, threads, 0, stream>>>(X, rewards, pk, dvp, T);

    if (mode0) {
        scan_kernel<0><<<NBLK, WAVE, 0, stream>>>(Winit, X, pk, dvp, sink, T);
        int Tv = T & ~7;
        if (Tv > 0) {
            int nthr = Tv / 8;
            final_vec<<<(nthr + 255) / 256, 256, 0, stream>>>((const half_t*)sink, out, T, Tv);
        }
        if (T > Tv) {
            final_sca<<<(T - Tv + 255) / 256, 256, 0, stream>>>((const half_t*)sink, out, T, Tv);
        }
    } else {
        scan_kernel<1><<<NBLK, WAVE, 0, stream>>>(Winit, X, pk, dvp, sink, T);
        final_part<<<blocks, threads, 0, stream>>>((const float*)sink, out, T);
    }
}

// Round 4
// 2668.287 us; speedup vs baseline: 1.6180x; 1.6180x over previous
//
#include <hip/hip_runtime.h>
#include <math.h>

#define LR_C 0.1f
#define WINDOW_C 10
#define NH 512
#define NBLK 8   // 512 units / 64 lanes
#define WAVE 64
#define ALPHA (-1.44269504088896340736f)  // -log2(e)
#define CHUNK 832  // multiple of 64 (staging) and 16 (BODY pairing)

typedef _Float16 half_t;

__device__ __forceinline__ void gld_lds16(const void* g, void* l) {
    __builtin_amdgcn_global_load_lds((const __attribute__((address_space(1))) void*)g,
                                     (__attribute__((address_space(3))) void*)l, 16, 0, 0);
}
__device__ __forceinline__ void gld_lds4(const void* g, void* l) {
    __builtin_amdgcn_global_load_lds((const __attribute__((address_space(1))) void*)g,
                                     (__attribute__((address_space(3))) void*)l, 4, 0, 0);
}

// Scaled space: W = ALPHA*w, y_t = W[t]·x_t, h_t = 1/(1+2^{y_t}),
// W[t+1] = W[t] + h_t*cx_t,  cx_t = ALPHA*LR*r_t*x_t.
// Lookahead: y_{t+1} = u_t + h_t*d_t,  u_t = W[t]·x_{t+1},  d_t = cx_t·x_{t+1}.
// prep: pk[t] = {x0[t+1], x1[t+1], cx0[t], cx1[t]},  dv[t] = cx·x[t+1]; zeros for t>=T.
__global__ void prep_kernel(const float* __restrict__ X,
                            const float* __restrict__ rewards,
                            float4* __restrict__ pk, float* __restrict__ dv,
                            int T, int Tpad) {
    int t = blockIdx.x * blockDim.x + threadIdx.x;
    if (t >= Tpad) return;
    if (t >= T) { pk[t] = make_float4(0.f, 0.f, 0.f, 0.f); dv[t] = 0.f; return; }
    int lo = t - (WINDOW_C - 1); if (lo < 0) lo = 0;
    float s = 0.0f;
    for (int k = lo; k <= t; ++k) s += rewards[k];
    float r = rewards[t] - s / (float)(t - lo + 1);
    float c = ALPHA * LR_C * r;
    float cx0 = c * X[2 * t];
    float cx1 = c * X[2 * t + 1];
    float xn0 = 0.0f, xn1 = 0.0f;
    if (t + 1 < T) { xn0 = X[2 * t + 2]; xn1 = X[2 * t + 3]; }
    pk[t] = make_float4(xn0, xn1, cx0, cx1);
    dv[t] = fmaf(cx1, xn1, cx0 * xn0);
}

// MODE 0 scan: LDS-staged operand stream (no SMEM in steady loop).
__global__ __launch_bounds__(WAVE) void scan_lds(const float* __restrict__ Winit,
                                                 const float* __restrict__ X,
                                                 const float4* __restrict__ pk,
                                                 const float* __restrict__ dv,
                                                 half_t* __restrict__ hall, int Tpad) {
    __shared__ float4 lpkA[CHUNK], lpkB[CHUNK];
    __shared__ float  ldvA[CHUNK], ldvB[CHUNK];
    const int lane = threadIdx.x;
    const int i = blockIdx.x * WAVE + lane;
    float W0 = ALPHA * Winit[2 * i];
    float W1 = ALPHA * Winit[2 * i + 1];
    float u = fmaf(W1, X[1], W0 * X[0]);   // y_0
    float h = 0.0f, dpv = 0.0f, cxp0 = 0.0f, cxp1 = 0.0f;
    half_t* __restrict__ hrow = hall + (size_t)i * Tpad;

    const int NC = Tpad / CHUNK;

    // stage chunk 0 -> buffers A
    #pragma unroll
    for (int k = 0; k < CHUNK / 64; ++k) gld_lds16(pk + k * 64 + lane, lpkA + k * 64);
    #pragma unroll
    for (int k = 0; k < CHUNK / 64; ++k) gld_lds4(dv + k * 64 + lane, ldvA + k * 64);

    float4 pA[8], pB[8], dA[2], dB[2];
    float hh[8];

#define BODY(P, D, TT)                                                   \
    {                                                                    \
        _Pragma("unroll")                                                \
        for (int j = 0; j < 8; ++j) {                                    \
            float y = fmaf(h, dpv, u);           /* chain 1 */           \
            W0 = fmaf(h, cxp0, W0);              /* off-chain */         \
            W1 = fmaf(h, cxp1, W1);                                      \
            u = fmaf(W1, P[j].y, W0 * P[j].x);   /* off-chain */         \
            float e = __builtin_amdgcn_exp2f(y); /* chain 2 */           \
            h = __builtin_amdgcn_rcpf(1.0f + e); /* chain 3,4 */         \
            hh[j] = h;                                                   \
            cxp0 = P[j].z; cxp1 = P[j].w; dpv = D[j >> 2][j & 3];        \
        }                                                                \
        union { half_t hx[8]; float4 v; } cv;                            \
        _Pragma("unroll")                                                \
        for (int j = 0; j < 8; ++j) cv.hx[j] = (half_t)hh[j];            \
        *(float4*)(hrow + (TT)) = cv.v;                                  \
    }

    for (int c = 0; c < NC; ++c) {
        __builtin_amdgcn_s_waitcnt(0);        // staging of current chunk is done
        __builtin_amdgcn_sched_barrier(0);
        const float4* lp = (c & 1) ? lpkB : lpkA;
        const float4* lv = (const float4*)((c & 1) ? ldvB : ldvA);
        if (c + 1 < NC) {                     // issue next-chunk staging now;
            float4* np = (c & 1) ? lpkA : lpkB;   // completes during this chunk
            float*  nv = (c & 1) ? ldvA : ldvB;
            const float4* gp = pk + (size_t)(c + 1) * CHUNK;
            const float*  gv = dv + (size_t)(c + 1) * CHUNK;
            #pragma unroll
            for (int k = 0; k < CHUNK / 64; ++k) gld_lds16(gp + k * 64 + lane, np + k * 64);
            #pragma unroll
            for (int k = 0; k < CHUNK / 64; ++k) gld_lds4(gv + k * 64 + lane, nv + k * 64);
        }
        const int base = c * CHUNK;
        #pragma unroll
        for (int j = 0; j < 8; ++j) pA[j] = lp[j];
        dA[0] = lv[0]; dA[1] = lv[1];
        for (int s0 = 0; s0 < CHUNK; s0 += 16) {
            #pragma unroll
            for (int j = 0; j < 8; ++j) pB[j] = lp[s0 + 8 + j];
            dB[0] = lv[(s0 >> 2) + 2]; dB[1] = lv[(s0 >> 2) + 3];
            BODY(pA, dA, base + s0)
            if (s0 + 16 < CHUNK) {
                #pragma unroll
                for (int j = 0; j < 8; ++j) pA[j] = lp[s0 + 16 + j];
                dA[0] = lv[(s0 >> 2) + 4]; dA[1] = lv[(s0 >> 2) + 5];
            }
            BODY(pB, dB, base + s0 + 8)
        }
    }
#undef BODY
}

// MODE 1 fallback (small ws): per-iter loads + in-wave reduction.
__global__ __launch_bounds__(WAVE) void scan_simple(const float* __restrict__ Winit,
                                                    const float* __restrict__ X,
                                                    const float4* __restrict__ pk,
                                                    const float* __restrict__ dv,
                                                    float* __restrict__ partial, int T) {
    const int lane = threadIdx.x;
    const int b = blockIdx.x;
    const int i = b * WAVE + lane;
    float W0 = ALPHA * Winit[2 * i];
    float W1 = ALPHA * Winit[2 * i + 1];
    float u = fmaf(W1, X[1], W0 * X[0]);
    float h = 0.0f, dpv = 0.0f, cxp0 = 0.0f, cxp1 = 0.0f;
    float* __restrict__ prow = partial + (size_t)b * T;
    for (int t = 0; t < T; ++t) {
        float4 p = pk[t];
        float d = dv[t];
        float y = fmaf(h, dpv, u);
        W0 = fmaf(h, cxp0, W0);
        W1 = fmaf(h, cxp1, W1);
        u = fmaf(W1, p.y, W0 * p.x);
        float e = __builtin_amdgcn_exp2f(y);
        h = __builtin_amdgcn_rcpf(1.0f + e);
        float s = h;
        #pragma unroll
        for (int m = 1; m < WAVE; m <<= 1) s += __shfl_xor(s, m, WAVE);
        if (lane == 0) prow[t] = s;
        cxp0 = p.z; cxp1 = p.w; dpv = d;
    }
}

__global__ __launch_bounds__(256) void final_vec(const half_t* __restrict__ hall,
                                                 float* __restrict__ out, int Tpad, int Tv) {
    int g = blockIdx.x * blockDim.x + threadIdx.x;
    int t0 = g * 8;
    if (t0 >= Tv) return;
    float s[8] = {0, 0, 0, 0, 0, 0, 0, 0};
    for (int u = 0; u < NH; ++u) {
        union { float4 v; half_t hx[8]; } cv;
        cv.v = *(const float4*)(hall + (size_t)u * Tpad + t0);
        #pragma unroll
        for (int j = 0; j < 8; ++j) s[j] += (float)cv.hx[j];
    }
    const float inv = 1.0f / (float)NH;
    float4 o0 = make_float4(s[0] * inv, s[1] * inv, s[2] * inv, s[3] * inv);
    float4 o1 = make_float4(s[4] * inv, s[5] * inv, s[6] * inv, s[7] * inv);
    *(float4*)(out + t0) = o0;
    *(float4*)(out + t0 + 4) = o1;
}

__global__ void final_sca(const half_t* __restrict__ hall,
                          float* __restrict__ out, int Tpad, int T, int tstart) {
    int t = tstart + blockIdx.x * blockDim.x + threadIdx.x;
    if (t >= T) return;
    float s = 0.0f;
    for (int u = 0; u < NH; ++u) s += (float)hall[(size_t)u * Tpad + t];
    out[t] = s * (1.0f / (float)NH);
}

__global__ void final_part(const float* __restrict__ partial,
                           float* __restrict__ out, int T) {
    int t = blockIdx.x * blockDim.x + threadIdx.x;
    if (t >= T) return;
    float s = 0.0f;
    #pragma unroll
    for (int b = 0; b < NBLK; ++b) s += partial[(size_t)b * T + t];
    out[t] = s * (1.0f / (float)NH);
}

extern "C" void kernel_launch(void* const* d_in, const int* in_sizes, int n_in,
                              void* d_out, int out_size, void* d_ws, size_t ws_size,
                              hipStream_t stream) {
    const float* X       = (const float*)d_in[0];
    const float* rewards = (const float*)d_in[1];
    const float* Winit   = (const float*)d_in[2];
    float* out = (float*)d_out;
    const int T = in_sizes[1];
    const int Tpad = ((T + CHUNK - 1) / CHUNK) * CHUNK;

    float4* pk   = (float4*)d_ws;
    float*  dvp  = (float*)((char*)d_ws + 16ull * (size_t)Tpad);
    void*   sink = (void*)((char*)d_ws + 20ull * (size_t)Tpad);

    const size_t need0 = 20ull * Tpad + 2ull * NH * Tpad;   // pk+dv + fp16 hall (~105 MB)
    const bool mode0 = (ws_size >= need0);

    int threads = 256;
    prep_kernel<<<(Tpad + threads - 1) / threads, threads, 0, stream>>>(
        X, rewards, pk, dvp, T, Tpad);

    if (mode0) {
        scan_lds<<<NBLK, WAVE, 0, stream>>>(Winit, X, pk, dvp, (half_t*)sink, Tpad);
        int Tv = T & ~7;
        if (Tv > 0)
            final_vec<<<(Tv / 8 + 255) / 256, 256, 0, stream>>>((const half_t*)sink, out, Tpad, Tv);
        if (T > Tv)
            final_sca<<<(T - Tv + 255) / 256, 256, 0, stream>>>((const half_t*)sink, out, Tpad, T, Tv);
    } else {
        scan_simple<<<NBLK, WAVE, 0, stream>>>(Winit, X, pk, dvp, (float*)sink, T);
        final_part<<<(T + threads - 1) / threads, threads, 0, stream>>>((const float*)sink, out, T);
    }
}